// Round 2
// baseline (223.130 us; speedup 1.0000x reference)
//
#include <hip/hip_runtime.h>
#include <cmath>

// RestorationLoss = (1 - mean(SSIM(r_low, r_high))) + mean((r_low - r_high)^2)
// SSIM: depthwise 11x11 gaussian convs, zero-padded SAME, separable.
// Trick: only 4 conv arrays needed: mu1, mu2, conv(x1^2+x2^2), conv(x1*x2).
// Fused: out = 1 + sum(d^2 - ssim_px) / Npix.

#define HH 512
#define WW 512
#define TILE_H 32
#define TILE_W 64
#define HB (TILE_H + 10)                          // 42 halo rows
#define NPLANES 48                                // 16 * 3
#define CT (WW / TILE_W)                          // 8
#define RT (HH / TILE_H)                          // 16
#define NBLOCKS (NPLANES * RT * CT)               // 6144

struct GW { float g[11]; };

__global__ __launch_bounds__(256, 3)
void ssim_main(const float* __restrict__ img1, const float* __restrict__ img2,
               float* __restrict__ partial, GW gw)
{
    __shared__ float hbuf[4][HB][TILE_W];         // 43008 B: 3 blocks/CU
    __shared__ float red[4];

    const int tid   = threadIdx.x;
    const int bx    = blockIdx.x;                 // col tile 0..7
    const int by    = blockIdx.y;                 // row tile 0..15
    const int plane = blockIdx.z;                 // 0..47
    const int row0  = by * TILE_H;
    const int col0  = bx * TILE_W;
    const float* p1 = img1 + (size_t)plane * (HH * WW);
    const float* p2 = img2 + (size_t)plane * (HH * WW);

    // interior: all halo reads in-bounds (reads span rows row0-5..row0+36, cols col0-8..col0+71)
    const bool interior = (bx > 0) && (bx < CT - 1) && (by > 0) && (by < RT - 1);

    // ---- Phase 1: horizontal conv (global -> registers -> LDS) ----
    {
        const int cg = tid & 15;                  // col group: tile cols 4cg..4cg+3
        const int rs = tid >> 4;                  // row slot 0..15
        for (int rl = rs; rl < HB; rl += 16) {
            const int grow  = row0 - 5 + rl;
            const int cbase = col0 + 4 * cg - 8;  // 16B-aligned window start (20 floats)
            float x1[20], x2[20];
            if (interior) {
                const float4* q1 = reinterpret_cast<const float4*>(p1 + (size_t)grow * WW + cbase);
                const float4* q2 = reinterpret_cast<const float4*>(p2 + (size_t)grow * WW + cbase);
                #pragma unroll
                for (int v = 0; v < 5; ++v) {
                    float4 a = q1[v], b = q2[v];
                    x1[4*v+0] = a.x; x1[4*v+1] = a.y; x1[4*v+2] = a.z; x1[4*v+3] = a.w;
                    x2[4*v+0] = b.x; x2[4*v+1] = b.y; x2[4*v+2] = b.z; x2[4*v+3] = b.w;
                }
            } else {
                // clamp + mask-multiply implements zero padding branchlessly
                const int   growc = min(max(grow, 0), HH - 1);
                const float rmask = (grow >= 0 && grow < HH) ? 1.f : 0.f;
                const float* r1 = p1 + (size_t)growc * WW;
                const float* r2 = p2 + (size_t)growc * WW;
                #pragma unroll
                for (int e = 0; e < 20; ++e) {
                    int   gc  = cbase + e;
                    int   gcc = min(max(gc, 0), WW - 1);
                    float m   = (gc >= 0 && gc < WW) ? rmask : 0.f;
                    x1[e] = r1[gcc] * m;
                    x2[e] = r2[gcc] * m;
                }
            }
            float acc[4][4];
            #pragma unroll
            for (int k = 0; k < 4; ++k)
                #pragma unroll
                for (int i = 0; i < 4; ++i) acc[k][i] = 0.f;
            // out col i taps element e = i + j + 3 (j = gaussian tap index)
            #pragma unroll
            for (int e = 3; e <= 16; ++e) {
                float a  = x1[e], b = x2[e];
                float v2 = a * a + b * b;
                float v3 = a * b;
                #pragma unroll
                for (int i = 0; i < 4; ++i) {
                    int j = e - 3 - i;
                    if (j >= 0 && j < 11) {
                        float w = gw.g[j];
                        acc[0][i] += w * a;
                        acc[1][i] += w * b;
                        acc[2][i] += w * v2;
                        acc[3][i] += w * v3;
                    }
                }
            }
            #pragma unroll
            for (int k = 0; k < 4; ++k) {
                *reinterpret_cast<float4*>(&hbuf[k][rl][4 * cg]) =
                    make_float4(acc[k][0], acc[k][1], acc[k][2], acc[k][3]);
            }
        }
    }
    __syncthreads();

    // ---- Phase 2: vertical conv + ssim + mse ----
    float local = 0.f;
    {
        const int tx = tid & 63;                  // column
        const int rg = tid >> 6;                  // rows rg*8 .. rg*8+7
        float res[4][8];
        #pragma unroll
        for (int k = 0; k < 4; ++k) {
            float win[18];
            #pragma unroll
            for (int t = 0; t < 18; ++t) win[t] = hbuf[k][rg * 8 + t][tx];
            #pragma unroll
            for (int p = 0; p < 8; ++p) {
                float s = 0.f;
                #pragma unroll
                for (int j = 0; j < 11; ++j) s += gw.g[j] * win[p + j];
                res[k][p] = s;
            }
        }
        const float C1c = 0.0001f, C2c = 0.0009f;
        #pragma unroll
        for (int p = 0; p < 8; ++p) {
            int   r   = rg * 8 + p;
            float mu1 = res[0][p], mu2 = res[1][p];
            float S   = res[2][p], P   = res[3][p];
            float m11 = mu1 * mu1, m22 = mu2 * mu2, m12 = mu1 * mu2;
            float num = (2.f * m12 + C1c) * (2.f * (P - m12) + C2c);
            float den = (m11 + m22 + C1c) * ((S - m11 - m22) + C2c);
            float ssim = num / den;
            size_t off = (size_t)(row0 + r) * WW + col0 + tx;
            float a = p1[off], b = p2[off];
            float d = a - b;
            local += d * d - ssim;
        }
    }

    // ---- block reduce (wave shuffle + LDS across 4 waves) ----
    #pragma unroll
    for (int off = 32; off > 0; off >>= 1) local += __shfl_down(local, off);
    if ((tid & 63) == 0) red[tid >> 6] = local;
    __syncthreads();
    if (tid == 0) {
        int bid = (plane * RT + by) * CT + bx;
        partial[bid] = (red[0] + red[1]) + (red[2] + red[3]);
    }
}

__global__ __launch_bounds__(256)
void ssim_finish(const float* __restrict__ partial, float* __restrict__ out)
{
    __shared__ float red[256];
    float s = 0.f;
    for (int i = threadIdx.x; i < NBLOCKS; i += 256) s += partial[i];
    red[threadIdx.x] = s;
    __syncthreads();
    for (int step = 128; step > 0; step >>= 1) {
        if ((int)threadIdx.x < step) red[threadIdx.x] += red[threadIdx.x + step];
        __syncthreads();
    }
    if (threadIdx.x == 0)
        out[0] = 1.0f + red[0] * (1.0f / 12582912.0f);
}

extern "C" void kernel_launch(void* const* d_in, const int* in_sizes, int n_in,
                              void* d_out, int out_size, void* d_ws, size_t ws_size,
                              hipStream_t stream)
{
    const float* r_low  = (const float*)d_in[0];
    const float* r_high = (const float*)d_in[1];
    float* out     = (float*)d_out;
    float* partial = (float*)d_ws;                // 6144 floats = 24 KB scratch

    GW gw;                                        // gaussian weights -> SGPRs via kernarg
    {
        float s = 0.f;
        for (int i = 0; i < 11; ++i) {
            float c = (float)(i - 5);
            gw.g[i] = expf(-(c * c) / 4.5f);      // 2*sigma^2 = 4.5
            s += gw.g[i];
        }
        for (int i = 0; i < 11; ++i) gw.g[i] /= s;
    }

    dim3 grid(CT, RT, NPLANES);
    ssim_main<<<grid, dim3(256), 0, stream>>>(r_low, r_high, partial, gw);
    ssim_finish<<<1, dim3(256), 0, stream>>>(partial, out);
}